// Round 2
// baseline (1538.407 us; speedup 1.0000x reference)
//
#include <hip/hip_runtime.h>
#include <hip/hip_fp16.h>

// TGCN forward, algebraically reduced (H0 = 0 => R/Wr dead, Z*H = 0):
//   deg[d] = #in-edges of d ; dinv = rsqrt(deg+1)
//   xs[s]  = fp16( x[s] * dinv[s] )
//   agg[d] = bf16( dinv[d] * ( sum_{e: dst=d} xs[src] + xs[d]*dinv[d] ) )
//   M = [Wz@Lzw_top | Wh@Lhw_top]  (64x512, bf16, MFMA B-layout), cb = bias fold
//   out = softmax(relu((1-Z)*Ht) @ Wo + bo), Z/Ht from agg@M via MFMA
//
// R1 -> R2: atomic scatter (2700us) -> CSR build + register gather.
// R3 -> R4: scatter 16x write amp -> 2-level bucket sort (793 -> 455us).
// R7 -> R8: node GEMM -> mfma_f32_16x16x32_bf16 (412 -> off top-5).
// R13 -> R14: global-cursor atomics -> deterministic offsets (315 -> 304).
// R14 -> R15: epilogue fp32 divides -> v_rcp_f32 (304 -> 275.7).
// R15 -> R16: 9 -> 6 launches. NEUTRAL (281.5): graph capture already
// amortizes launches => the ~228us middle is real exec time across 5
// kernels, all just below gather's 53.5. Middle is NOT BW-bound
// (ideal traffic ~115MB ~ 20us) -> bound by scattered 4B stores.
// R16 -> R17: kill the csr round-trip. finalize's 3.2M scattered csr
// stores + 12.8MB write + gather's 12.8MB read existed only to get a
// node-sorted edge order for register accumulation. Instead: per-bucket
// fp32 LDS accumulation via ds_add_f32 directly at packed dstLocal
// (205M LDS atomics ~ 10-16us, hidden under the 53us random xs reads).
// finalize -> prep (deg/dinv/xs only, no scatter phase); gather -> agg
// (2 blocks/bucket node-halves, [128][65] fp32 = 33KB LDS, 4 blk/CU).
// fp16 -> fp32 edge accumulation: absmax should improve.

#define SHIFT 8
#define NPB   256          // nodes per bucket (=1<<SHIFT)
#define BMAX  512          // max buckets (n <= 131072 for 17-bit src packing)
#define TILE  8192         // edges per tile (hist/scatter blocks)
#define MBBLK 64           // fused build_m blocks (512 j-cols / 8 per block)

typedef __attribute__((ext_vector_type(8))) short short8;
typedef __attribute__((ext_vector_type(4))) float floatx4;

__device__ __forceinline__ ushort f2b(float f) {   // fp32 -> bf16 RNE
    union { float f; unsigned u; } v; v.f = f;
    unsigned r = v.u + 0x7FFFu + ((v.u >> 16) & 1u);
    return (ushort)(r >> 16);
}

__device__ __forceinline__ float fastrcp(float x) {  // v_rcp_f32, ~1e-5 rel err
    return __builtin_amdgcn_rcpf(x);
}

// blocks [0,nT): per-tile bucket histogram -> histg[block][bucket]
// blocks [nT,nT+MBBLK): weight fold  Mb[j][k] = bf16(sum_t W[k][t]*L[t][j])
__global__ __launch_bounds__(512) void hist_build_kernel(
    const int* __restrict__ dsts, int* __restrict__ histg, int E, int B, int nT,
    const float* __restrict__ Wz, const float* __restrict__ bz,
    const float* __restrict__ Wh, const float* __restrict__ bh,
    const float* __restrict__ Lzw, const float* __restrict__ Lzb,
    const float* __restrict__ Lhw, const float* __restrict__ Lhb,
    ushort* __restrict__ Mb, float* __restrict__ cb) {
    __shared__ int h[BMAX];
    if (blockIdx.x < nT) {
        for (int i = threadIdx.x; i < B; i += 512) h[i] = 0;
        __syncthreads();
        int tile0 = blockIdx.x * TILE;
#pragma unroll 4
        for (int j = 0; j < TILE / 512; ++j) {
            int e = tile0 + j * 512 + threadIdx.x;
            if (e < E) atomicAdd(&h[((unsigned)dsts[e]) >> SHIFT], 1);
        }
        __syncthreads();
        for (int i = threadIdx.x; i < B; i += 512)
            histg[blockIdx.x * BMAX + i] = h[i];
    } else {
        int j = (blockIdx.x - nT) * 8 + (threadIdx.x >> 6);   // 0..511
        int k = threadIdx.x & 63;                             // 0..63
        int which = j >> 8;
        int jj = j & 255;
        const float* W  = which ? Wh  : Wz;
        const float* bv = which ? bh  : bz;
        const float* L  = which ? Lhw : Lzw;   // [512,256]; rows 0..255 (H0=0)
        const float* Lb = which ? Lhb : Lzb;
        float acc = 0.f;
        for (int t = 0; t < 256; ++t) acc = fmaf(W[k * 256 + t], L[t * 256 + jj], acc);
        Mb[j * 64 + k] = f2b(acc);
        if (k == 0) {
            float a = 0.f;
            for (int t = 0; t < 256; ++t) a = fmaf(bv[t], L[t * 256 + jj], a);
            cb[j] = a + Lb[jj];
        }
    }
}

// one block per bucket: exclusive scan of histg[.][b] over blocks (in place),
// column total -> bdeg[b]
__global__ __launch_bounds__(512) void colscan_kernel(int* __restrict__ histg,
                                                      int* __restrict__ bdeg,
                                                      int nT) {
    int b = blockIdx.x;
    int tid = threadIdx.x;
    __shared__ int sv[512];
    int v = (tid < nT) ? histg[tid * BMAX + b] : 0;
    sv[tid] = v;
    __syncthreads();
    for (int off = 1; off < 512; off <<= 1) {
        int t = (tid >= off) ? sv[tid - off] : 0;
        __syncthreads();
        sv[tid] += t;
        __syncthreads();
    }
    if (tid < nT) histg[tid * BMAX + b] = sv[tid] - v;   // exclusive
    if (tid == 0) bdeg[b] = sv[511];                      // column total
}

// tile scatter with deterministic run bases (bbase[b] + histg[blk][b]) and
// LDS-only cursors — no global atomics. bbase recomputed per block by an
// inline LDS scan of bdeg. Packed (dstLocal<<17 | src).
__global__ __launch_bounds__(512) void scatter2_kernel(const int* __restrict__ srcs,
                                                       const int* __restrict__ dsts,
                                                       const int* __restrict__ histg,
                                                       const int* __restrict__ bdeg,
                                                       int* __restrict__ staging,
                                                       int E, int B) {
    __shared__ int cur[BMAX];
    __shared__ int sv[BMAX];
    int tid = threadIdx.x;
    int v = (tid < B) ? bdeg[tid] : 0;
    sv[tid] = v;
    __syncthreads();
    for (int off = 1; off < BMAX; off <<= 1) {
        int t = (tid >= off) ? sv[tid - off] : 0;
        __syncthreads();
        sv[tid] += t;
        __syncthreads();
    }
    if (tid < B)
        cur[tid] = (sv[tid] - v) + histg[blockIdx.x * BMAX + tid];
    __syncthreads();
    int tile0 = blockIdx.x * TILE;
#pragma unroll 4
    for (int j = 0; j < TILE / 512; ++j) {
        int e = tile0 + j * 512 + threadIdx.x;
        if (e < E) {
            int d = dsts[e], s = srcs[e];
            int b = ((unsigned)d) >> SHIFT;
            int pos = atomicAdd(&cur[b], 1);   // LDS atomic only
            staging[pos] = ((d & (NPB - 1)) << 17) | s;
        }
    }
}

// one block per bucket: per-node LDS histogram -> deg/dinv, then write the
// bucket's xs rows: xs[s][c] = fp16(x[s][c]*dinv[s]). NO csr sort/scatter.
__global__ __launch_bounds__(512) void prep_kernel(const int* __restrict__ staging,
                                                   const int* __restrict__ bdeg,
                                                   const float* __restrict__ x,
                                                   float* __restrict__ dinv,
                                                   __half* __restrict__ xs,
                                                   int n, int B) {
    int b = blockIdx.x;
    int tid = threadIdx.x;
    __shared__ int sv[BMAX];
    __shared__ int nd[NPB];
    __shared__ float sdinv[NPB];
    if (tid < NPB) nd[tid] = 0;
    int v = (tid < B) ? bdeg[tid] : 0;
    sv[tid] = v;
    __syncthreads();
    for (int off = 1; off < BMAX; off <<= 1) {
        int t = (tid >= off) ? sv[tid - off] : 0;
        __syncthreads();
        sv[tid] += t;
        __syncthreads();
    }
    int count = bdeg[b];
    int base  = sv[b] - count;        // exclusive bucket base
    for (int i = tid; i < count; i += 512)
        atomicAdd(&nd[staging[base + i] >> 17], 1);
    __syncthreads();
    if (tid < NPB) {
        float dn = rsqrtf((float)nd[tid] + 1.0f);
        sdinv[tid] = dn;
        int node = (b << SHIFT) + tid;
        if (node < n) dinv[node] = dn;
    }
    __syncthreads();
    int nbase = b << SHIFT;
    for (int i2 = tid; i2 < NPB * 16; i2 += 512) {
        int nl = i2 >> 4;
        int node = nbase + nl;
        if (node < n) {
            float dn = sdinv[nl];
            size_t gi = (size_t)node * 16 + (i2 & 15);
            float4 vx = ((const float4*)x)[gi];
            __half2 a = __floats2half2_rn(vx.x * dn, vx.y * dn);
            __half2 c = __floats2half2_rn(vx.z * dn, vx.w * dn);
            ((__half2*)xs)[gi * 2 + 0] = a;
            ((__half2*)xs)[gi * 2 + 1] = c;
        }
    }
}

// 2 blocks per bucket (node-halves). Per block: scan staging window, for
// edges in this half accumulate xs[src] into a [128][65] fp32 LDS plane via
// ds_add_f32 (no ordering needed -> no csr). 8 lanes/edge, 16B xs chunk per
// lane; 65-float row pad spreads banks by random dstLocal. Epilogue folds
// the self-loop + dinv scale and emits bf16 agg rows.
__global__ __launch_bounds__(512) void agg_kernel(const int* __restrict__ staging,
                                                  const int* __restrict__ bdeg,
                                                  const __half* __restrict__ xs,
                                                  const float* __restrict__ dinv,
                                                  ushort* __restrict__ aggb,
                                                  int n, int B) {
    int b    = blockIdx.x >> 1;
    int half = blockIdx.x & 1;
    int tid  = threadIdx.x;
    __shared__ int sv[BMAX];
    __shared__ float sdinv[128];
    __shared__ float agg[128 * 65];    // 33.3 KB, row pad 65 for bank spread
    int v = (tid < B) ? bdeg[tid] : 0;
    sv[tid] = v;
    __syncthreads();
    for (int off = 1; off < BMAX; off <<= 1) {
        int t = (tid >= off) ? sv[tid - off] : 0;
        __syncthreads();
        sv[tid] += t;
        __syncthreads();
    }
    int count = bdeg[b];
    int base  = sv[b] - count;
    if (tid < 128) {
        int node = (b << SHIFT) + (half << 7) + tid;
        sdinv[tid] = (node < n) ? dinv[node] : 0.f;
    }
    for (int i = tid; i < 128 * 65; i += 512) agg[i] = 0.f;
    __syncthreads();
    int g = tid >> 3;        // edge slot 0..63
    int c = tid & 7;         // 16B chunk of the xs row
    for (int i = g; i < count; i += 64) {
        int p  = staging[base + i];       // 8 lanes/group broadcast-load
        int dl = p >> 17;
        if ((dl >> 7) == half) {
            int s = p & 0x1FFFF;
            union { uint4 u; __half2 h[4]; } q;
            q.u = *(const uint4*)(xs + (size_t)s * 64 + c * 8);
            float* ap = &agg[(dl & 127) * 65 + c * 8];
#pragma unroll
            for (int t = 0; t < 4; ++t) {
                float2 f = __half22float2(q.h[t]);
                atomicAdd(ap + 2 * t,     f.x);   // ds_add_f32
                atomicAdd(ap + 2 * t + 1, f.y);
            }
        }
    }
    __syncthreads();
    // epilogue: agg_out = bf16( dinv*(acc + xs_self*dinv) ), coalesced write
    for (int i = tid; i < 128 * 8; i += 512) {
        int nl = i >> 3;
        int cc = i & 7;
        int node = (b << SHIFT) + (half << 7) + nl;
        if (node >= n) continue;
        float dn = sdinv[nl];
        const float* ap = &agg[nl * 65 + cc * 8];
        union { uint4 u; __half2 h[4]; } q;
        q.u = *(const uint4*)(xs + (size_t)node * 64 + cc * 8);
        uint4 o;
        unsigned* ow = (unsigned*)&o;
#pragma unroll
        for (int t = 0; t < 4; ++t) {
            float2 f = __half22float2(q.h[t]);
            float v0 = dn * fmaf(f.x, dn, ap[2 * t]);
            float v1 = dn * fmaf(f.y, dn, ap[2 * t + 1]);
            ow[t] = (unsigned)f2b(v0) | ((unsigned)f2b(v1) << 16);
        }
        ((uint4*)(aggb + (size_t)node * 64))[cc] = o;
    }
}

// 512 threads = 8 waves. Wave w owns cols w*32..w*32+31 for BOTH gates
// (z and ht meet in-register, h=relu((1-z)*ht) -> one h-plane in LDS).
__global__ __launch_bounds__(512) void node_mfma_kernel(
    const ushort* __restrict__ aggb,   // [n][64] bf16
    const ushort* __restrict__ Mb,     // [512][64] bf16 (B layout)
    const float* __restrict__ cb,      // [512]
    const float* __restrict__ Wo, const float* __restrict__ bo,
    float* __restrict__ out, int n) {
    int tid  = threadIdx.x;
    int w    = tid >> 6;
    int lane = tid & 63;
    int nidx = lane & 15;
    int quad = lane >> 4;
    short8 bfz[2][2], bfh[2][2];
    float cbz[2], cbh[2];
#pragma unroll
    for (int cg = 0; cg < 2; ++cg) {
        int colZ = (w << 5) + (cg << 4) + nidx;
        int colH = 256 + colZ;
#pragma unroll
        for (int s = 0; s < 2; ++s) {
            bfz[cg][s] = *(const short8*)(Mb + colZ * 64 + s * 32 + quad * 8);
            bfh[cg][s] = *(const short8*)(Mb + colH * 64 + s * 32 + quad * 8);
        }
        cbz[cg] = cb[colZ];
        cbh[cg] = cb[colH];
    }
    __shared__ float sH[32][260];    // 33 KB h-plane (260 pad: 2-way on stores)
    __shared__ float sWo[4][256];
    if (tid < 256) {
#pragma unroll
        for (int o = 0; o < 4; ++o) sWo[o][tid] = Wo[tid * 4 + o];
    }
    float bo0 = bo[0], bo1 = bo[1], bo2 = bo[2], bo3 = bo[3];
    int ntiles = (n + 31) >> 5;
    for (int tile = blockIdx.x; tile < ntiles; tile += gridDim.x) {
        int node0 = tile << 5;
        int nA0 = node0 + nidx;
        int nA1 = node0 + 16 + nidx;
        if (nA0 >= n) nA0 = n - 1;   // clamp; stores are guarded
        if (nA1 >= n) nA1 = n - 1;
        const ushort* ar0 = aggb + (size_t)nA0 * 64;
        const ushort* ar1 = aggb + (size_t)nA1 * 64;
        short8 a00 = *(const short8*)(ar0 + quad * 8);
        short8 a01 = *(const short8*)(ar0 + 32 + quad * 8);
        short8 a10 = *(const short8*)(ar1 + quad * 8);
        short8 a11 = *(const short8*)(ar1 + 32 + quad * 8);
#pragma unroll
        for (int cg = 0; cg < 2; ++cg) {
            int col = (w << 5) + (cg << 4) + nidx;
#pragma unroll
            for (int grp = 0; grp < 2; ++grp) {
                short8 a0 = grp ? a10 : a00;
                short8 a1 = grp ? a11 : a01;
                floatx4 cz = {cbz[cg], cbz[cg], cbz[cg], cbz[cg]};
                cz = __builtin_amdgcn_mfma_f32_16x16x32_bf16(a0, bfz[cg][0], cz, 0, 0, 0);
                cz = __builtin_amdgcn_mfma_f32_16x16x32_bf16(a1, bfz[cg][1], cz, 0, 0, 0);
                floatx4 chh = {cbh[cg], cbh[cg], cbh[cg], cbh[cg]};
                chh = __builtin_amdgcn_mfma_f32_16x16x32_bf16(a0, bfh[cg][0], chh, 0, 0, 0);
                chh = __builtin_amdgcn_mfma_f32_16x16x32_bf16(a1, bfh[cg][1], chh, 0, 0, 0);
#pragma unroll
                for (int r = 0; r < 4; ++r) {
                    int row = (grp << 4) + (quad << 2) + r;   // node within tile
                    float zc = fastrcp(1.0f + __expf(cz[r]));     // 1 - sigmoid
                    float th = 1.0f - 2.0f * fastrcp(1.0f + __expf(2.0f * chh[r]));
                    sH[row][col] = fmaxf(zc * th, 0.0f);
                }
            }
        }
        __syncthreads();
        {   // head: 16 threads per node, 16 channels each
            int nb = tid >> 4, g = tid & 15;
            float l0 = 0.f, l1 = 0.f, l2 = 0.f, l3 = 0.f;
#pragma unroll
            for (int ii = 0; ii < 16; ++ii) {
                int ch = g + 16 * ii;
                float hv = sH[nb][ch];
                l0 = fmaf(hv, sWo[0][ch], l0);
                l1 = fmaf(hv, sWo[1][ch], l1);
                l2 = fmaf(hv, sWo[2][ch], l2);
                l3 = fmaf(hv, sWo[3][ch], l3);
            }
#pragma unroll
            for (int off = 8; off > 0; off >>= 1) {
                l0 += __shfl_down(l0, off, 16);
                l1 += __shfl_down(l1, off, 16);
                l2 += __shfl_down(l2, off, 16);
                l3 += __shfl_down(l3, off, 16);
            }
            int node = node0 + nb;
            if (g == 0 && node < n) {
                float v0 = l0 + bo0, v1 = l1 + bo1, v2 = l2 + bo2, v3 = l3 + bo3;
                float mx = fmaxf(fmaxf(v0, v1), fmaxf(v2, v3));
                float e0 = __expf(v0 - mx), e1 = __expf(v1 - mx);
                float e2 = __expf(v2 - mx), e3 = __expf(v3 - mx);
                float inv = fastrcp(e0 + e1 + e2 + e3);
                float4 o;
                o.x = e0 * inv; o.y = e1 * inv; o.z = e2 * inv; o.w = e3 * inv;
                ((float4*)out)[node] = o;
            }
        }
        __syncthreads();
    }
}

extern "C" void kernel_launch(void* const* d_in, const int* in_sizes, int n_in,
                              void* d_out, int out_size, void* d_ws, size_t ws_size,
                              hipStream_t stream) {
    const float* x   = (const float*)d_in[0];
    const int*  eidx = (const int*)d_in[1];
    const float* Wz  = (const float*)d_in[2];
    const float* bz  = (const float*)d_in[3];
    // d_in[4]=Wr, d_in[5]=br : dead (H0 = 0)
    const float* Wh  = (const float*)d_in[6];
    const float* bh  = (const float*)d_in[7];
    const float* Lzw = (const float*)d_in[8];
    const float* Lzb = (const float*)d_in[9];
    // d_in[10]=Lrw, d_in[11]=Lrb : dead
    const float* Lhw = (const float*)d_in[12];
    const float* Lhb = (const float*)d_in[13];
    const float* Wo  = (const float*)d_in[14];
    const float* bo  = (const float*)d_in[15];
    float* out = (float*)d_out;

    int n = in_sizes[0] / 64;
    int E = in_sizes[1] / 2;
    const int* srcs = eidx;
    const int* dsts = eidx + E;
    int B = (n + NPB - 1) >> SHIFT;
    int nT = (E + TILE - 1) / TILE;          // tiles (<= 512 for E <= 4.2M)

    size_t na = ((size_t)n + 3) & ~(size_t)3;
    size_t stageBytes = ((size_t)E * 4 + 255) & ~(size_t)255;
    size_t aggBytes   = (((size_t)n * 64 * 2) + 255) & ~(size_t)255;

    char* ws = (char*)d_ws;
    float* dinv  = (float*)ws;  ws += na * 4;
    int*   bdeg  = (int*)ws;    ws += BMAX * 4;
    int*   histg = (int*)ws;    ws += (size_t)nT * BMAX * 4;
    int*   staging = (int*)ws;  ws += stageBytes;       // live through agg
    __half* xs   = (__half*)ws; ws += (size_t)n * 64 * 2;
    ushort* aggb = (ushort*)ws; ws += aggBytes;         // no longer aliases
    ushort* Mb   = (ushort*)ws; ws += 512 * 64 * 2;
    float* cb    = (float*)ws;  ws += 512 * 4;

    hist_build_kernel<<<nT + MBBLK, 512, 0, stream>>>(dsts, histg, E, B, nT,
                                                      Wz, bz, Wh, bh,
                                                      Lzw, Lzb, Lhw, Lhb, Mb, cb);
    colscan_kernel<<<B, 512, 0, stream>>>(histg, bdeg, nT);
    scatter2_kernel<<<nT, 512, 0, stream>>>(srcs, dsts, histg, bdeg, staging,
                                            E, B);
    prep_kernel<<<B, 512, 0, stream>>>(staging, bdeg, x, dinv, xs, n, B);
    agg_kernel<<<2 * B, 512, 0, stream>>>(staging, bdeg, xs, dinv, aggb, n, B);
    node_mfma_kernel<<<1024, 512, 0, stream>>>(aggb, Mb, cb, Wo, bo, out, n);
}

// Round 3
// 375.704 us; speedup vs baseline: 4.0947x; 4.0947x over previous
//
#include <hip/hip_runtime.h>
#include <hip/hip_fp16.h>

// TGCN forward, algebraically reduced (H0 = 0 => R/Wr dead, Z*H = 0):
//   deg[d] = #in-edges of d ; dinv = rsqrt(deg+1)
//   xs[s]  = fp16( x[s] * dinv[s] )
//   agg[d] = bf16( dinv[d] * ( sum_{e: dst=d} xs[src] + xs[d]*dinv[d] ) )
//   M = [Wz@Lzw_top | Wh@Lhw_top]  (64x512, bf16, MFMA B-layout), cb = bias fold
//   out = softmax(relu((1-Z)*Ht) @ Wo + bo), Z/Ht from agg@M via MFMA
//
// R1 -> R2: atomic scatter (2700us) -> CSR build + register gather.
// R3 -> R4: scatter 16x write amp -> 2-level bucket sort (793 -> 455us).
// R7 -> R8: node GEMM -> mfma_f32_16x16x32_bf16 (412 -> off top-5).
// R13 -> R14: global-cursor atomics -> deterministic offsets (315 -> 304).
// R14 -> R15: epilogue fp32 divides -> v_rcp_f32 (304 -> 275.7).
// R15 -> R16: 9 -> 6 launches. NEUTRAL => graph capture amortizes launches;
// the ~222us middle is real exec time, every mid kernel just under 53us.
// R16 -> R17: LDS ds_add_f32 accumulation. DISASTER (1339us): 1024
// serialized dependent LDS atomics/thread, VALUBusy 2%. Lesson: LDS atomics
// only as occasional ops, never the per-element accumulation primitive.
// R17 -> R18: revert to R16 structure; kill the csr ROUND-TRIP instead.
// deg via 3.2M global int atomics fused into hist's dsts pass (L2 atomics,
// ~64x fewer than R1's per-channel float version). bucket_gather fuses the
// within-bucket counting sort into gather: csr lives in LDS only (31KB,
// 60 sigma headroom), scattered stores go to LDS, gather reads indices via
// LDS broadcast. Removes finalize's count pass (12.8MB + 3.2M LDS atomics),
// the 12.8MB scattered csr write, the 12.8MB csr read, and one kernel.
// gather numerics unchanged (fp16 accumulate, bf16 RNE out).

#define SHIFT 8
#define NPB   256          // nodes per bucket (=1<<SHIFT)
#define BMAX  512          // max buckets (n <= 131072 for 17-bit src packing)
#define TILE  8192         // edges per tile (hist/scatter blocks)
#define MBBLK 64           // fused build_m blocks (512 j-cols / 8 per block)
#define CAP   7936         // LDS csr entries per half-bucket (mean 4096, sd 64)

typedef __attribute__((ext_vector_type(8))) short short8;
typedef __attribute__((ext_vector_type(4))) float floatx4;

__device__ __forceinline__ ushort f2b(float f) {   // fp32 -> bf16 RNE
    union { float f; unsigned u; } v; v.f = f;
    unsigned r = v.u + 0x7FFFu + ((v.u >> 16) & 1u);
    return (ushort)(r >> 16);
}

__device__ __forceinline__ float fastrcp(float x) {  // v_rcp_f32, ~1e-5 rel err
    return __builtin_amdgcn_rcpf(x);
}

// blocks [0,nT): per-tile bucket histogram -> histg[block][bucket], plus
//   per-node deg via global int atomics (deg pre-zeroed by memset).
// blocks [nT,nT+MBBLK): weight fold  Mb[j][k] = bf16(sum_t W[k][t]*L[t][j])
__global__ __launch_bounds__(512) void hist_build_kernel(
    const int* __restrict__ dsts, int* __restrict__ histg,
    int* __restrict__ deg, int E, int B, int nT,
    const float* __restrict__ Wz, const float* __restrict__ bz,
    const float* __restrict__ Wh, const float* __restrict__ bh,
    const float* __restrict__ Lzw, const float* __restrict__ Lzb,
    const float* __restrict__ Lhw, const float* __restrict__ Lhb,
    ushort* __restrict__ Mb, float* __restrict__ cb) {
    __shared__ int h[BMAX];
    if (blockIdx.x < nT) {
        for (int i = threadIdx.x; i < B; i += 512) h[i] = 0;
        __syncthreads();
        int tile0 = blockIdx.x * TILE;
#pragma unroll 4
        for (int j = 0; j < TILE / 512; ++j) {
            int e = tile0 + j * 512 + threadIdx.x;
            if (e < E) {
                int d = dsts[e];
                atomicAdd(&h[((unsigned)d) >> SHIFT], 1);
                atomicAdd(&deg[d], 1);           // L2 atomic, no return
            }
        }
        __syncthreads();
        for (int i = threadIdx.x; i < B; i += 512)
            histg[blockIdx.x * BMAX + i] = h[i];
    } else {
        int j = (blockIdx.x - nT) * 8 + (threadIdx.x >> 6);   // 0..511
        int k = threadIdx.x & 63;                             // 0..63
        int which = j >> 8;
        int jj = j & 255;
        const float* W  = which ? Wh  : Wz;
        const float* bv = which ? bh  : bz;
        const float* L  = which ? Lhw : Lzw;   // [512,256]; rows 0..255 (H0=0)
        const float* Lb = which ? Lhb : Lzb;
        float acc = 0.f;
        for (int t = 0; t < 256; ++t) acc = fmaf(W[k * 256 + t], L[t * 256 + jj], acc);
        Mb[j * 64 + k] = f2b(acc);
        if (k == 0) {
            float a = 0.f;
            for (int t = 0; t < 256; ++t) a = fmaf(bv[t], L[t * 256 + jj], a);
            cb[j] = a + Lb[jj];
        }
    }
}

// one block per bucket: exclusive scan of histg[.][b] over blocks (in place),
// column total -> bdeg[b]
__global__ __launch_bounds__(512) void colscan_kernel(int* __restrict__ histg,
                                                      int* __restrict__ bdeg,
                                                      int nT) {
    int b = blockIdx.x;
    int tid = threadIdx.x;
    __shared__ int sv[512];
    int v = (tid < nT) ? histg[tid * BMAX + b] : 0;
    sv[tid] = v;
    __syncthreads();
    for (int off = 1; off < 512; off <<= 1) {
        int t = (tid >= off) ? sv[tid - off] : 0;
        __syncthreads();
        sv[tid] += t;
        __syncthreads();
    }
    if (tid < nT) histg[tid * BMAX + b] = sv[tid] - v;   // exclusive
    if (tid == 0) bdeg[b] = sv[511];                      // column total
}

// single block: bbase = exclusive scan of bdeg
__global__ __launch_bounds__(BMAX) void bucket_prefix_kernel(const int* __restrict__ bdeg,
                                                             int* __restrict__ bbase, int B) {
    __shared__ int sv[BMAX];
    int tid = threadIdx.x;
    int v = (tid < B) ? bdeg[tid] : 0;
    sv[tid] = v;
    __syncthreads();
    for (int off = 1; off < BMAX; off <<= 1) {
        int t = (tid >= off) ? sv[tid - off] : 0;
        __syncthreads();
        sv[tid] += t;
        __syncthreads();
    }
    if (tid < B) bbase[tid] = sv[tid] - v;
}

// xs[s][c] = fp16( x[s][c] * rsqrt(deg[s]+1) ) — one thread per 4 channels
__global__ __launch_bounds__(256) void xs_kernel(const float* __restrict__ x,
                                                 const int* __restrict__ deg,
                                                 __half* __restrict__ xs, int total) {
    int i = blockIdx.x * 256 + threadIdx.x;   // over n*16 float4 groups
    if (i >= total) return;
    float dn = rsqrtf((float)deg[i >> 4] + 1.0f);
    float4 v = ((const float4*)x)[i];
    __half2 a = __floats2half2_rn(v.x * dn, v.y * dn);
    __half2 b = __floats2half2_rn(v.z * dn, v.w * dn);
    ((__half2*)xs)[i * 2 + 0] = a;
    ((__half2*)xs)[i * 2 + 1] = b;
}

// tile scatter with deterministic run bases (bbase[b] + histg[blk][b]) and
// LDS-only cursors — no global atomics. Packed (dstLocal<<17 | src).
__global__ __launch_bounds__(512) void scatter2_kernel(const int* __restrict__ srcs,
                                                       const int* __restrict__ dsts,
                                                       const int* __restrict__ histg,
                                                       const int* __restrict__ bbase,
                                                       int* __restrict__ staging,
                                                       int E, int B) {
    __shared__ int cur[BMAX];
    int tid = threadIdx.x;
    if (tid < B) cur[tid] = bbase[tid] + histg[blockIdx.x * BMAX + tid];
    __syncthreads();
    int tile0 = blockIdx.x * TILE;
#pragma unroll 4
    for (int j = 0; j < TILE / 512; ++j) {
        int e = tile0 + j * 512 + threadIdx.x;
        if (e < E) {
            int d = dsts[e], s = srcs[e];
            int b = ((unsigned)d) >> SHIFT;
            int pos = atomicAdd(&cur[b], 1);   // LDS atomic only
            staging[pos] = ((d & (NPB - 1)) << 17) | s;
        }
    }
}

// 2 blocks per bucket (node-halves of 128). Counting sort INTO LDS:
// deg row -> scan -> cursor scatter of the bucket's staging window into
// csrl[CAP] (scattered stores hit LDS, not HBM). Then the register gather:
// wave w owns 16 nodes; lane = (edge_group 0..7) x (16B chunk 0..7); edge
// indices read via conflict-free LDS broadcast. fp16 accumulate, bf16 out.
__global__ __launch_bounds__(512) void bucket_gather_kernel(
    const int* __restrict__ staging,
    const int* __restrict__ bdeg,
    const int* __restrict__ bbase,
    const int* __restrict__ deg,
    const __half* __restrict__ xs,
    ushort* __restrict__ aggb, int n, int B) {
    int b    = blockIdx.x >> 1;
    int half = blockIdx.x & 1;
    int tid  = threadIdx.x;
    __shared__ int   csrl[CAP];
    __shared__ int   sstart[128];
    __shared__ int   ncur[128];
    __shared__ int   sdeg[128];
    __shared__ int   ssc[128];
    __shared__ float sdinv[128];
    int node0 = (b << SHIFT) + (half << 7);
    int count = bdeg[b];
    int base  = bbase[b];
    if (tid < 128) {
        int nodeid = node0 + tid;
        int dg = (nodeid < n) ? deg[nodeid] : 0;
        sdeg[tid] = dg;
        ssc[tid]  = dg;
        sdinv[tid] = rsqrtf((float)dg + 1.0f);
    }
    __syncthreads();
    for (int off = 1; off < 128; off <<= 1) {
        int t = 0;
        if (tid < 128 && tid >= off) t = ssc[tid - off];
        __syncthreads();
        if (tid < 128) ssc[tid] += t;
        __syncthreads();
    }
    if (tid < 128) {
        int excl = ssc[tid] - sdeg[tid];
        sstart[tid] = excl;
        ncur[tid]   = excl;
    }
    __syncthreads();
    // counting-sort scatter: one coalesced staging pass, LDS stores only
    for (int i = tid; i < count; i += 512) {
        int p  = staging[base + i];
        int dl = p >> 17;
        if ((dl >> 7) == half) {
            int pos = atomicAdd(&ncur[dl & 127], 1);
            if (pos < CAP) csrl[pos] = p & 0x1FFFF;   // never fires in practice
        }
    }
    __syncthreads();
    // register gather (identical numerics to the R16 gather kernel)
    int wv = tid >> 6, lane = tid & 63;
    int eg = lane >> 3;      // edge group 0..7
    int c  = lane & 7;       // 16B chunk (8 halfs)
    for (int t16 = 0; t16 < 16; ++t16) {
        int nl   = (wv << 4) + t16;
        int node = node0 + nl;
        int s0 = sstart[nl];
        int d  = sdeg[nl];
        __half2 hz = __float2half2_rn(0.f);
        __half2 hacc[4] = {hz, hz, hz, hz};
        int full = d & ~15;
        for (int be = 0; be < full; be += 16) {
            int qb = s0 + be;
            if (qb > CAP - 16) qb = CAP - 16;    // safety clamp, never binds
            int i0 = csrl[qb + eg];
            int i1 = csrl[qb + 8 + eg];
            union { uint4 u; __half2 h[4]; } p0, p1;
            p0.u = *(const uint4*)(xs + (size_t)i0 * 64 + c * 8);
            p1.u = *(const uint4*)(xs + (size_t)i1 * 64 + c * 8);
#pragma unroll
            for (int t = 0; t < 4; ++t) hacc[t] = __hadd2(hacc[t], p0.h[t]);
#pragma unroll
            for (int t = 0; t < 4; ++t) hacc[t] = __hadd2(hacc[t], p1.h[t]);
        }
        if (full < d) {   // ragged tail (< 16 edges)
            int e0 = full + eg;
            int e1 = full + 8 + eg;
            int q0 = s0 + (e0 < d ? e0 : d - 1);
            int q1 = s0 + (e1 < d ? e1 : d - 1);
            if (q0 > CAP - 1) q0 = CAP - 1;
            if (q1 > CAP - 1) q1 = CAP - 1;
            int i0 = csrl[q0];
            int i1 = csrl[q1];
            union { uint4 u; __half2 h[4]; } p0, p1;
            p0.u = *(const uint4*)(xs + (size_t)i0 * 64 + c * 8);
            p1.u = *(const uint4*)(xs + (size_t)i1 * 64 + c * 8);
            if (e0 >= d) p0.u = make_uint4(0u, 0u, 0u, 0u);
            if (e1 >= d) p1.u = make_uint4(0u, 0u, 0u, 0u);
#pragma unroll
            for (int t = 0; t < 4; ++t) hacc[t] = __hadd2(hacc[t], p0.h[t]);
#pragma unroll
            for (int t = 0; t < 4; ++t) hacc[t] = __hadd2(hacc[t], p1.h[t]);
        }
        // packed cross-lane reduce of the 8 edge groups down to eg==0
#pragma unroll
        for (int off = 32; off >= 8; off >>= 1) {
#pragma unroll
            for (int t = 0; t < 4; ++t) {
                union { __half2 h; int i; } u;
                u.h = hacc[t];
                u.i = __shfl_down(u.i, off);
                hacc[t] = __hadd2(hacc[t], u.h);
            }
        }
        if (eg == 0 && node < n) {
            float dn = sdinv[nl];
            union { uint4 u; __half2 h[4]; } p;
            p.u = *(const uint4*)(xs + (size_t)node * 64 + c * 8);
            uint4 o;
            unsigned* ow = (unsigned*)&o;
#pragma unroll
            for (int t = 0; t < 4; ++t) {
                float2 a = __half22float2(hacc[t]);
                float2 f = __half22float2(p.h[t]);
                float v0 = dn * fmaf(f.x, dn, a.x);
                float v1 = dn * fmaf(f.y, dn, a.y);
                ow[t] = (unsigned)f2b(v0) | ((unsigned)f2b(v1) << 16);
            }
            ((uint4*)(aggb + (size_t)node * 64))[c] = o;
        }
    }
}

// 512 threads = 8 waves. Wave w owns cols w*32..w*32+31 for BOTH gates
// (z and ht meet in-register, h=relu((1-z)*ht) -> one h-plane in LDS).
__global__ __launch_bounds__(512) void node_mfma_kernel(
    const ushort* __restrict__ aggb,   // [n][64] bf16
    const ushort* __restrict__ Mb,     // [512][64] bf16 (B layout)
    const float* __restrict__ cb,      // [512]
    const float* __restrict__ Wo, const float* __restrict__ bo,
    float* __restrict__ out, int n) {
    int tid  = threadIdx.x;
    int w    = tid >> 6;
    int lane = tid & 63;
    int nidx = lane & 15;
    int quad = lane >> 4;
    short8 bfz[2][2], bfh[2][2];
    float cbz[2], cbh[2];
#pragma unroll
    for (int cg = 0; cg < 2; ++cg) {
        int colZ = (w << 5) + (cg << 4) + nidx;
        int colH = 256 + colZ;
#pragma unroll
        for (int s = 0; s < 2; ++s) {
            bfz[cg][s] = *(const short8*)(Mb + colZ * 64 + s * 32 + quad * 8);
            bfh[cg][s] = *(const short8*)(Mb + colH * 64 + s * 32 + quad * 8);
        }
        cbz[cg] = cb[colZ];
        cbh[cg] = cb[colH];
    }
    __shared__ float sH[32][260];    // 33 KB h-plane (260 pad: 2-way on stores)
    __shared__ float sWo[4][256];
    if (tid < 256) {
#pragma unroll
        for (int o = 0; o < 4; ++o) sWo[o][tid] = Wo[tid * 4 + o];
    }
    float bo0 = bo[0], bo1 = bo[1], bo2 = bo[2], bo3 = bo[3];
    int ntiles = (n + 31) >> 5;
    for (int tile = blockIdx.x; tile < ntiles; tile += gridDim.x) {
        int node0 = tile << 5;
        int nA0 = node0 + nidx;
        int nA1 = node0 + 16 + nidx;
        if (nA0 >= n) nA0 = n - 1;   // clamp; stores are guarded
        if (nA1 >= n) nA1 = n - 1;
        const ushort* ar0 = aggb + (size_t)nA0 * 64;
        const ushort* ar1 = aggb + (size_t)nA1 * 64;
        short8 a00 = *(const short8*)(ar0 + quad * 8);
        short8 a01 = *(const short8*)(ar0 + 32 + quad * 8);
        short8 a10 = *(const short8*)(ar1 + quad * 8);
        short8 a11 = *(const short8*)(ar1 + 32 + quad * 8);
#pragma unroll
        for (int cg = 0; cg < 2; ++cg) {
            int col = (w << 5) + (cg << 4) + nidx;
#pragma unroll
            for (int grp = 0; grp < 2; ++grp) {
                short8 a0 = grp ? a10 : a00;
                short8 a1 = grp ? a11 : a01;
                floatx4 cz = {cbz[cg], cbz[cg], cbz[cg], cbz[cg]};
                cz = __builtin_amdgcn_mfma_f32_16x16x32_bf16(a0, bfz[cg][0], cz, 0, 0, 0);
                cz = __builtin_amdgcn_mfma_f32_16x16x32_bf16(a1, bfz[cg][1], cz, 0, 0, 0);
                floatx4 chh = {cbh[cg], cbh[cg], cbh[cg], cbh[cg]};
                chh = __builtin_amdgcn_mfma_f32_16x16x32_bf16(a0, bfh[cg][0], chh, 0, 0, 0);
                chh = __builtin_amdgcn_mfma_f32_16x16x32_bf16(a1, bfh[cg][1], chh, 0, 0, 0);
#pragma unroll
                for (int r = 0; r < 4; ++r) {
                    int row = (grp << 4) + (quad << 2) + r;   // node within tile
                    float zc = fastrcp(1.0f + __expf(cz[r]));     // 1 - sigmoid
                    float th = 1.0f - 2.0f * fastrcp(1.0f + __expf(2.0f * chh[r]));
                    sH[row][col] = fmaxf(zc * th, 0.0f);
                }
            }
        }
        __syncthreads();
        {   // head: 16 threads per node, 16 channels each
            int nb = tid >> 4, g = tid & 15;
            float l0 = 0.f, l1 = 0.f, l2 = 0.f, l3 = 0.f;
#pragma unroll
            for (int ii = 0; ii < 16; ++ii) {
                int ch = g + 16 * ii;
                float hv = sH[nb][ch];
                l0 = fmaf(hv, sWo[0][ch], l0);
                l1 = fmaf(hv, sWo[1][ch], l1);
                l2 = fmaf(hv, sWo[2][ch], l2);
                l3 = fmaf(hv, sWo[3][ch], l3);
            }
#pragma unroll
            for (int off = 8; off > 0; off >>= 1) {
                l0 += __shfl_down(l0, off, 16);
                l1 += __shfl_down(l1, off, 16);
                l2 += __shfl_down(l2, off, 16);
                l3 += __shfl_down(l3, off, 16);
            }
            int node = node0 + nb;
            if (g == 0 && node < n) {
                float v0 = l0 + bo0, v1 = l1 + bo1, v2 = l2 + bo2, v3 = l3 + bo3;
                float mx = fmaxf(fmaxf(v0, v1), fmaxf(v2, v3));
                float e0 = __expf(v0 - mx), e1 = __expf(v1 - mx);
                float e2 = __expf(v2 - mx), e3 = __expf(v3 - mx);
                float inv = fastrcp(e0 + e1 + e2 + e3);
                float4 o;
                o.x = e0 * inv; o.y = e1 * inv; o.z = e2 * inv; o.w = e3 * inv;
                ((float4*)out)[node] = o;
            }
        }
        __syncthreads();
    }
}

extern "C" void kernel_launch(void* const* d_in, const int* in_sizes, int n_in,
                              void* d_out, int out_size, void* d_ws, size_t ws_size,
                              hipStream_t stream) {
    const float* x   = (const float*)d_in[0];
    const int*  eidx = (const int*)d_in[1];
    const float* Wz  = (const float*)d_in[2];
    const float* bz  = (const float*)d_in[3];
    // d_in[4]=Wr, d_in[5]=br : dead (H0 = 0)
    const float* Wh  = (const float*)d_in[6];
    const float* bh  = (const float*)d_in[7];
    const float* Lzw = (const float*)d_in[8];
    const float* Lzb = (const float*)d_in[9];
    // d_in[10]=Lrw, d_in[11]=Lrb : dead
    const float* Lhw = (const float*)d_in[12];
    const float* Lhb = (const float*)d_in[13];
    const float* Wo  = (const float*)d_in[14];
    const float* bo  = (const float*)d_in[15];
    float* out = (float*)d_out;

    int n = in_sizes[0] / 64;
    int E = in_sizes[1] / 2;
    const int* srcs = eidx;
    const int* dsts = eidx + E;
    int B = (n + NPB - 1) >> SHIFT;
    int nT = (E + TILE - 1) / TILE;          // tiles (<= 512 for E <= 4.2M)

    size_t na = ((size_t)n + 3) & ~(size_t)3;
    size_t stageBytes = ((size_t)E * 4 + 255) & ~(size_t)255;
    size_t aggBytes   = (((size_t)n * 64 * 2) + 255) & ~(size_t)255;

    char* ws = (char*)d_ws;
    int*   deg   = (int*)ws;    ws += na * 4;
    int*   bdeg  = (int*)ws;    ws += BMAX * 4;
    int*   bbase = (int*)ws;    ws += BMAX * 4;
    int*   histg = (int*)ws;    ws += (size_t)nT * BMAX * 4;
    int*   staging = (int*)ws;  ws += stageBytes;       // live through gather
    __half* xs   = (__half*)ws; ws += (size_t)n * 64 * 2;
    ushort* aggb = (ushort*)ws; ws += aggBytes;
    ushort* Mb   = (ushort*)ws; ws += 512 * 64 * 2;
    float* cb    = (float*)ws;  ws += 512 * 4;

    hipMemsetAsync(deg, 0, na * 4, stream);
    hist_build_kernel<<<nT + MBBLK, 512, 0, stream>>>(dsts, histg, deg, E, B, nT,
                                                      Wz, bz, Wh, bh,
                                                      Lzw, Lzb, Lhw, Lhb, Mb, cb);
    colscan_kernel<<<B, 512, 0, stream>>>(histg, bdeg, nT);
    bucket_prefix_kernel<<<1, BMAX, 0, stream>>>(bdeg, bbase, B);
    xs_kernel<<<(n * 16 + 255) / 256, 256, 0, stream>>>(x, deg, xs, n * 16);
    scatter2_kernel<<<nT, 512, 0, stream>>>(srcs, dsts, histg, bbase, staging,
                                            E, B);
    bucket_gather_kernel<<<2 * B, 512, 0, stream>>>(staging, bdeg, bbase, deg,
                                                    xs, aggb, n, B);
    node_mfma_kernel<<<1024, 512, 0, stream>>>(aggb, Mb, cb, Wo, bo, out, n);
}

// Round 4
// 264.482 us; speedup vs baseline: 5.8167x; 1.4205x over previous
//
#include <hip/hip_runtime.h>
#include <hip/hip_fp16.h>

// TGCN forward, algebraically reduced (H0 = 0 => R/Wr dead, Z*H = 0):
//   deg[d] = #in-edges of d ; dinv = rsqrt(deg+1)
//   xs[s]  = fp16( x[s] * dinv[s] )
//   agg[d] = bf16( dinv[d] * ( sum_{e: dst=d} xs[src] + xs[d]*dinv[d] ) )
//   M = [Wz@Lzw_top | Wh@Lhw_top]  (64x512, bf16, MFMA B-layout), cb = bias fold
//   out = softmax(relu((1-Z)*Ht) @ Wo + bo), Z/Ht from agg@M via MFMA
//
// R1 -> R2: atomic scatter (2700us) -> CSR build + register gather.
// R3 -> R4: scatter 16x write amp -> 2-level bucket sort (793 -> 455us).
// R7 -> R8: node GEMM -> mfma_f32_16x16x32_bf16 (412 -> off top-5).
// R13 -> R14: global-cursor atomics -> deterministic offsets (315 -> 304).
// R14 -> R15: epilogue fp32 divides -> v_rcp_f32 (304 -> 275.7).
// R15 -> R16: 9 -> 6 launches. NEUTRAL => graph capture amortizes launches;
// middle is real exec time, every mid kernel just under 53us.
// R16 -> R17: LDS ds_add_f32 per-element accumulation. DISASTER (1339us):
// serialized dependent LDS atomics, VALUBusy 2%. Lesson: LDS atomics only
// as occasional ops (histogram counts), never the accumulation primitive.
// R17 -> R18: LDS-resident csr in bucket_gather (kills csr HBM round-trip,
// ~ -25us) BUT deg via 3.2M scattered global atomics = 130us hist
// (WRITE_SIZE 100MB = 3.2M x 32B: device-scope atomics bypass the
// non-coherent per-XCD L2s -> memory-side round trip each). Lesson logged.
// R18 -> R19: keep LDS-csr bucket_gather; deg counted per-bucket from the
// sorted staging window via LDS histogram atomics in prep (16/thread, the
// proven R16-finalize pattern), which also emits xs. Global dinv deleted.

#define SHIFT 8
#define NPB   256          // nodes per bucket (=1<<SHIFT)
#define BMAX  512          // max buckets (n <= 131072 for 17-bit src packing)
#define TILE  8192         // edges per tile (hist/scatter blocks)
#define MBBLK 64           // fused build_m blocks (512 j-cols / 8 per block)
#define CAP   7936         // LDS csr entries per half-bucket (mean 4096, sd 64)

typedef __attribute__((ext_vector_type(8))) short short8;
typedef __attribute__((ext_vector_type(4))) float floatx4;

__device__ __forceinline__ ushort f2b(float f) {   // fp32 -> bf16 RNE
    union { float f; unsigned u; } v; v.f = f;
    unsigned r = v.u + 0x7FFFu + ((v.u >> 16) & 1u);
    return (ushort)(r >> 16);
}

__device__ __forceinline__ float fastrcp(float x) {  // v_rcp_f32, ~1e-5 rel err
    return __builtin_amdgcn_rcpf(x);
}

// blocks [0,nT): per-tile bucket histogram -> histg[block][bucket]
// blocks [nT,nT+MBBLK): weight fold  Mb[j][k] = bf16(sum_t W[k][t]*L[t][j])
__global__ __launch_bounds__(512) void hist_build_kernel(
    const int* __restrict__ dsts, int* __restrict__ histg, int E, int B, int nT,
    const float* __restrict__ Wz, const float* __restrict__ bz,
    const float* __restrict__ Wh, const float* __restrict__ bh,
    const float* __restrict__ Lzw, const float* __restrict__ Lzb,
    const float* __restrict__ Lhw, const float* __restrict__ Lhb,
    ushort* __restrict__ Mb, float* __restrict__ cb) {
    __shared__ int h[BMAX];
    if (blockIdx.x < nT) {
        for (int i = threadIdx.x; i < B; i += 512) h[i] = 0;
        __syncthreads();
        int tile0 = blockIdx.x * TILE;
#pragma unroll 4
        for (int j = 0; j < TILE / 512; ++j) {
            int e = tile0 + j * 512 + threadIdx.x;
            if (e < E) atomicAdd(&h[((unsigned)dsts[e]) >> SHIFT], 1);
        }
        __syncthreads();
        for (int i = threadIdx.x; i < B; i += 512)
            histg[blockIdx.x * BMAX + i] = h[i];
    } else {
        int j = (blockIdx.x - nT) * 8 + (threadIdx.x >> 6);   // 0..511
        int k = threadIdx.x & 63;                             // 0..63
        int which = j >> 8;
        int jj = j & 255;
        const float* W  = which ? Wh  : Wz;
        const float* bv = which ? bh  : bz;
        const float* L  = which ? Lhw : Lzw;   // [512,256]; rows 0..255 (H0=0)
        const float* Lb = which ? Lhb : Lzb;
        float acc = 0.f;
        for (int t = 0; t < 256; ++t) acc = fmaf(W[k * 256 + t], L[t * 256 + jj], acc);
        Mb[j * 64 + k] = f2b(acc);
        if (k == 0) {
            float a = 0.f;
            for (int t = 0; t < 256; ++t) a = fmaf(bv[t], L[t * 256 + jj], a);
            cb[j] = a + Lb[jj];
        }
    }
}

// one block per bucket: exclusive scan of histg[.][b] over blocks (in place),
// column total -> bdeg[b]
__global__ __launch_bounds__(512) void colscan_kernel(int* __restrict__ histg,
                                                      int* __restrict__ bdeg,
                                                      int nT) {
    int b = blockIdx.x;
    int tid = threadIdx.x;
    __shared__ int sv[512];
    int v = (tid < nT) ? histg[tid * BMAX + b] : 0;
    sv[tid] = v;
    __syncthreads();
    for (int off = 1; off < 512; off <<= 1) {
        int t = (tid >= off) ? sv[tid - off] : 0;
        __syncthreads();
        sv[tid] += t;
        __syncthreads();
    }
    if (tid < nT) histg[tid * BMAX + b] = sv[tid] - v;   // exclusive
    if (tid == 0) bdeg[b] = sv[511];                      // column total
}

// single block: bbase = exclusive scan of bdeg
__global__ __launch_bounds__(BMAX) void bucket_prefix_kernel(const int* __restrict__ bdeg,
                                                             int* __restrict__ bbase, int B) {
    __shared__ int sv[BMAX];
    int tid = threadIdx.x;
    int v = (tid < B) ? bdeg[tid] : 0;
    sv[tid] = v;
    __syncthreads();
    for (int off = 1; off < BMAX; off <<= 1) {
        int t = (tid >= off) ? sv[tid - off] : 0;
        __syncthreads();
        sv[tid] += t;
        __syncthreads();
    }
    if (tid < B) bbase[tid] = sv[tid] - v;
}

// tile scatter with deterministic run bases (bbase[b] + histg[blk][b]) and
// LDS-only cursors — no global atomics. Packed (dstLocal<<17 | src).
__global__ __launch_bounds__(512) void scatter2_kernel(const int* __restrict__ srcs,
                                                       const int* __restrict__ dsts,
                                                       const int* __restrict__ histg,
                                                       const int* __restrict__ bbase,
                                                       int* __restrict__ staging,
                                                       int E, int B) {
    __shared__ int cur[BMAX];
    int tid = threadIdx.x;
    if (tid < B) cur[tid] = bbase[tid] + histg[blockIdx.x * BMAX + tid];
    __syncthreads();
    int tile0 = blockIdx.x * TILE;
#pragma unroll 4
    for (int j = 0; j < TILE / 512; ++j) {
        int e = tile0 + j * 512 + threadIdx.x;
        if (e < E) {
            int d = dsts[e], s = srcs[e];
            int b = ((unsigned)d) >> SHIFT;
            int pos = atomicAdd(&cur[b], 1);   // LDS atomic only
            staging[pos] = ((d & (NPB - 1)) << 17) | s;
        }
    }
}

// one block per bucket: deg counted from the bucket's staging window via
// LDS histogram atomics (16/thread), deg written coalesced; then the
// bucket's xs rows: xs[s][c] = fp16(x[s][c]*dinv[s]) (dinv in LDS only).
__global__ __launch_bounds__(512) void prep_kernel(const int* __restrict__ staging,
                                                   const int* __restrict__ bdeg,
                                                   const int* __restrict__ bbase,
                                                   const float* __restrict__ x,
                                                   int* __restrict__ deg,
                                                   __half* __restrict__ xs,
                                                   int n, int B) {
    int b = blockIdx.x;
    int tid = threadIdx.x;
    __shared__ int nd[NPB];
    __shared__ float sdinv[NPB];
    if (tid < NPB) nd[tid] = 0;
    __syncthreads();
    int count = bdeg[b];
    int base  = bbase[b];
    for (int i = tid; i < count; i += 512)
        atomicAdd(&nd[staging[base + i] >> 17], 1);
    __syncthreads();
    if (tid < NPB) {
        int dg = nd[tid];
        float dn = rsqrtf((float)dg + 1.0f);
        sdinv[tid] = dn;
        int node = (b << SHIFT) + tid;
        if (node < n) deg[node] = dg;
    }
    __syncthreads();
    int nbase = b << SHIFT;
    for (int i2 = tid; i2 < NPB * 16; i2 += 512) {
        int nl = i2 >> 4;
        int node = nbase + nl;
        if (node < n) {
            float dn = sdinv[nl];
            size_t gi = (size_t)node * 16 + (i2 & 15);
            float4 vx = ((const float4*)x)[gi];
            __half2 a = __floats2half2_rn(vx.x * dn, vx.y * dn);
            __half2 c = __floats2half2_rn(vx.z * dn, vx.w * dn);
            ((__half2*)xs)[gi * 2 + 0] = a;
            ((__half2*)xs)[gi * 2 + 1] = c;
        }
    }
}

// 2 blocks per bucket (node-halves of 128). Counting sort INTO LDS:
// deg row -> scan -> cursor scatter of the bucket's staging window into
// csrl[CAP] (scattered stores hit LDS, not HBM). Then the register gather:
// wave w owns 16 nodes; lane = (edge_group 0..7) x (16B chunk 0..7); edge
// indices read via conflict-free LDS broadcast. fp16 accumulate, bf16 out.
__global__ __launch_bounds__(512) void bucket_gather_kernel(
    const int* __restrict__ staging,
    const int* __restrict__ bdeg,
    const int* __restrict__ bbase,
    const int* __restrict__ deg,
    const __half* __restrict__ xs,
    ushort* __restrict__ aggb, int n, int B) {
    int b    = blockIdx.x >> 1;
    int half = blockIdx.x & 1;
    int tid  = threadIdx.x;
    __shared__ int   csrl[CAP];
    __shared__ int   sstart[128];
    __shared__ int   ncur[128];
    __shared__ int   sdeg[128];
    __shared__ int   ssc[128];
    __shared__ float sdinv[128];
    int node0 = (b << SHIFT) + (half << 7);
    int count = bdeg[b];
    int base  = bbase[b];
    if (tid < 128) {
        int nodeid = node0 + tid;
        int dg = (nodeid < n) ? deg[nodeid] : 0;
        sdeg[tid] = dg;
        ssc[tid]  = dg;
        sdinv[tid] = rsqrtf((float)dg + 1.0f);
    }
    __syncthreads();
    for (int off = 1; off < 128; off <<= 1) {
        int t = 0;
        if (tid < 128 && tid >= off) t = ssc[tid - off];
        __syncthreads();
        if (tid < 128) ssc[tid] += t;
        __syncthreads();
    }
    if (tid < 128) {
        int excl = ssc[tid] - sdeg[tid];
        sstart[tid] = excl;
        ncur[tid]   = excl;
    }
    __syncthreads();
    // counting-sort scatter: one coalesced staging pass, LDS stores only
    for (int i = tid; i < count; i += 512) {
        int p  = staging[base + i];
        int dl = p >> 17;
        if ((dl >> 7) == half) {
            int pos = atomicAdd(&ncur[dl & 127], 1);
            if (pos < CAP) csrl[pos] = p & 0x1FFFF;   // never fires in practice
        }
    }
    __syncthreads();
    // register gather (identical numerics to the R16 gather kernel)
    int wv = tid >> 6, lane = tid & 63;
    int eg = lane >> 3;      // edge group 0..7
    int c  = lane & 7;       // 16B chunk (8 halfs)
    for (int t16 = 0; t16 < 16; ++t16) {
        int nl   = (wv << 4) + t16;
        int node = node0 + nl;
        int s0 = sstart[nl];
        int d  = sdeg[nl];
        __half2 hz = __float2half2_rn(0.f);
        __half2 hacc[4] = {hz, hz, hz, hz};
        int full = d & ~15;
        for (int be = 0; be < full; be += 16) {
            int qb = s0 + be;
            if (qb > CAP - 16) qb = CAP - 16;    // safety clamp, never binds
            int i0 = csrl[qb + eg];
            int i1 = csrl[qb + 8 + eg];
            union { uint4 u; __half2 h[4]; } p0, p1;
            p0.u = *(const uint4*)(xs + (size_t)i0 * 64 + c * 8);
            p1.u = *(const uint4*)(xs + (size_t)i1 * 64 + c * 8);
#pragma unroll
            for (int t = 0; t < 4; ++t) hacc[t] = __hadd2(hacc[t], p0.h[t]);
#pragma unroll
            for (int t = 0; t < 4; ++t) hacc[t] = __hadd2(hacc[t], p1.h[t]);
        }
        if (full < d) {   // ragged tail (< 16 edges)
            int e0 = full + eg;
            int e1 = full + 8 + eg;
            int q0 = s0 + (e0 < d ? e0 : d - 1);
            int q1 = s0 + (e1 < d ? e1 : d - 1);
            if (q0 > CAP - 1) q0 = CAP - 1;
            if (q1 > CAP - 1) q1 = CAP - 1;
            int i0 = csrl[q0];
            int i1 = csrl[q1];
            union { uint4 u; __half2 h[4]; } p0, p1;
            p0.u = *(const uint4*)(xs + (size_t)i0 * 64 + c * 8);
            p1.u = *(const uint4*)(xs + (size_t)i1 * 64 + c * 8);
            if (e0 >= d) p0.u = make_uint4(0u, 0u, 0u, 0u);
            if (e1 >= d) p1.u = make_uint4(0u, 0u, 0u, 0u);
#pragma unroll
            for (int t = 0; t < 4; ++t) hacc[t] = __hadd2(hacc[t], p0.h[t]);
#pragma unroll
            for (int t = 0; t < 4; ++t) hacc[t] = __hadd2(hacc[t], p1.h[t]);
        }
        // packed cross-lane reduce of the 8 edge groups down to eg==0
#pragma unroll
        for (int off = 32; off >= 8; off >>= 1) {
#pragma unroll
            for (int t = 0; t < 4; ++t) {
                union { __half2 h; int i; } u;
                u.h = hacc[t];
                u.i = __shfl_down(u.i, off);
                hacc[t] = __hadd2(hacc[t], u.h);
            }
        }
        if (eg == 0 && node < n) {
            float dn = sdinv[nl];
            union { uint4 u; __half2 h[4]; } p;
            p.u = *(const uint4*)(xs + (size_t)node * 64 + c * 8);
            uint4 o;
            unsigned* ow = (unsigned*)&o;
#pragma unroll
            for (int t = 0; t < 4; ++t) {
                float2 a = __half22float2(hacc[t]);
                float2 f = __half22float2(p.h[t]);
                float v0 = dn * fmaf(f.x, dn, a.x);
                float v1 = dn * fmaf(f.y, dn, a.y);
                ow[t] = (unsigned)f2b(v0) | ((unsigned)f2b(v1) << 16);
            }
            ((uint4*)(aggb + (size_t)node * 64))[c] = o;
        }
    }
}

// 512 threads = 8 waves. Wave w owns cols w*32..w*32+31 for BOTH gates
// (z and ht meet in-register, h=relu((1-z)*ht) -> one h-plane in LDS).
__global__ __launch_bounds__(512) void node_mfma_kernel(
    const ushort* __restrict__ aggb,   // [n][64] bf16
    const ushort* __restrict__ Mb,     // [512][64] bf16 (B layout)
    const float* __restrict__ cb,      // [512]
    const float* __restrict__ Wo, const float* __restrict__ bo,
    float* __restrict__ out, int n) {
    int tid  = threadIdx.x;
    int w    = tid >> 6;
    int lane = tid & 63;
    int nidx = lane & 15;
    int quad = lane >> 4;
    short8 bfz[2][2], bfh[2][2];
    float cbz[2], cbh[2];
#pragma unroll
    for (int cg = 0; cg < 2; ++cg) {
        int colZ = (w << 5) + (cg << 4) + nidx;
        int colH = 256 + colZ;
#pragma unroll
        for (int s = 0; s < 2; ++s) {
            bfz[cg][s] = *(const short8*)(Mb + colZ * 64 + s * 32 + quad * 8);
            bfh[cg][s] = *(const short8*)(Mb + colH * 64 + s * 32 + quad * 8);
        }
        cbz[cg] = cb[colZ];
        cbh[cg] = cb[colH];
    }
    __shared__ float sH[32][260];    // 33 KB h-plane (260 pad: 2-way on stores)
    __shared__ float sWo[4][256];
    if (tid < 256) {
#pragma unroll
        for (int o = 0; o < 4; ++o) sWo[o][tid] = Wo[tid * 4 + o];
    }
    float bo0 = bo[0], bo1 = bo[1], bo2 = bo[2], bo3 = bo[3];
    int ntiles = (n + 31) >> 5;
    for (int tile = blockIdx.x; tile < ntiles; tile += gridDim.x) {
        int node0 = tile << 5;
        int nA0 = node0 + nidx;
        int nA1 = node0 + 16 + nidx;
        if (nA0 >= n) nA0 = n - 1;   // clamp; stores are guarded
        if (nA1 >= n) nA1 = n - 1;
        const ushort* ar0 = aggb + (size_t)nA0 * 64;
        const ushort* ar1 = aggb + (size_t)nA1 * 64;
        short8 a00 = *(const short8*)(ar0 + quad * 8);
        short8 a01 = *(const short8*)(ar0 + 32 + quad * 8);
        short8 a10 = *(const short8*)(ar1 + quad * 8);
        short8 a11 = *(const short8*)(ar1 + 32 + quad * 8);
#pragma unroll
        for (int cg = 0; cg < 2; ++cg) {
            int col = (w << 5) + (cg << 4) + nidx;
#pragma unroll
            for (int grp = 0; grp < 2; ++grp) {
                short8 a0 = grp ? a10 : a00;
                short8 a1 = grp ? a11 : a01;
                floatx4 cz = {cbz[cg], cbz[cg], cbz[cg], cbz[cg]};
                cz = __builtin_amdgcn_mfma_f32_16x16x32_bf16(a0, bfz[cg][0], cz, 0, 0, 0);
                cz = __builtin_amdgcn_mfma_f32_16x16x32_bf16(a1, bfz[cg][1], cz, 0, 0, 0);
                floatx4 chh = {cbh[cg], cbh[cg], cbh[cg], cbh[cg]};
                chh = __builtin_amdgcn_mfma_f32_16x16x32_bf16(a0, bfh[cg][0], chh, 0, 0, 0);
                chh = __builtin_amdgcn_mfma_f32_16x16x32_bf16(a1, bfh[cg][1], chh, 0, 0, 0);
#pragma unroll
                for (int r = 0; r < 4; ++r) {
                    int row = (grp << 4) + (quad << 2) + r;   // node within tile
                    float zc = fastrcp(1.0f + __expf(cz[r]));     // 1 - sigmoid
                    float th = 1.0f - 2.0f * fastrcp(1.0f + __expf(2.0f * chh[r]));
                    sH[row][col] = fmaxf(zc * th, 0.0f);
                }
            }
        }
        __syncthreads();
        {   // head: 16 threads per node, 16 channels each
            int nb = tid >> 4, g = tid & 15;
            float l0 = 0.f, l1 = 0.f, l2 = 0.f, l3 = 0.f;
#pragma unroll
            for (int ii = 0; ii < 16; ++ii) {
                int ch = g + 16 * ii;
                float hv = sH[nb][ch];
                l0 = fmaf(hv, sWo[0][ch], l0);
                l1 = fmaf(hv, sWo[1][ch], l1);
                l2 = fmaf(hv, sWo[2][ch], l2);
                l3 = fmaf(hv, sWo[3][ch], l3);
            }
#pragma unroll
            for (int off = 8; off > 0; off >>= 1) {
                l0 += __shfl_down(l0, off, 16);
                l1 += __shfl_down(l1, off, 16);
                l2 += __shfl_down(l2, off, 16);
                l3 += __shfl_down(l3, off, 16);
            }
            int node = node0 + nb;
            if (g == 0 && node < n) {
                float v0 = l0 + bo0, v1 = l1 + bo1, v2 = l2 + bo2, v3 = l3 + bo3;
                float mx = fmaxf(fmaxf(v0, v1), fmaxf(v2, v3));
                float e0 = __expf(v0 - mx), e1 = __expf(v1 - mx);
                float e2 = __expf(v2 - mx), e3 = __expf(v3 - mx);
                float inv = fastrcp(e0 + e1 + e2 + e3);
                float4 o;
                o.x = e0 * inv; o.y = e1 * inv; o.z = e2 * inv; o.w = e3 * inv;
                ((float4*)out)[node] = o;
            }
        }
        __syncthreads();
    }
}

extern "C" void kernel_launch(void* const* d_in, const int* in_sizes, int n_in,
                              void* d_out, int out_size, void* d_ws, size_t ws_size,
                              hipStream_t stream) {
    const float* x   = (const float*)d_in[0];
    const int*  eidx = (const int*)d_in[1];
    const float* Wz  = (const float*)d_in[2];
    const float* bz  = (const float*)d_in[3];
    // d_in[4]=Wr, d_in[5]=br : dead (H0 = 0)
    const float* Wh  = (const float*)d_in[6];
    const float* bh  = (const float*)d_in[7];
    const float* Lzw = (const float*)d_in[8];
    const float* Lzb = (const float*)d_in[9];
    // d_in[10]=Lrw, d_in[11]=Lrb : dead
    const float* Lhw = (const float*)d_in[12];
    const float* Lhb = (const float*)d_in[13];
    const float* Wo  = (const float*)d_in[14];
    const float* bo  = (const float*)d_in[15];
    float* out = (float*)d_out;

    int n = in_sizes[0] / 64;
    int E = in_sizes[1] / 2;
    const int* srcs = eidx;
    const int* dsts = eidx + E;
    int B = (n + NPB - 1) >> SHIFT;
    int nT = (E + TILE - 1) / TILE;          // tiles (<= 512 for E <= 4.2M)

    size_t na = ((size_t)n + 3) & ~(size_t)3;
    size_t stageBytes = ((size_t)E * 4 + 255) & ~(size_t)255;
    size_t aggBytes   = (((size_t)n * 64 * 2) + 255) & ~(size_t)255;

    char* ws = (char*)d_ws;
    int*   deg   = (int*)ws;    ws += na * 4;
    int*   bdeg  = (int*)ws;    ws += BMAX * 4;
    int*   bbase = (int*)ws;    ws += BMAX * 4;
    int*   histg = (int*)ws;    ws += (size_t)nT * BMAX * 4;
    int*   staging = (int*)ws;  ws += stageBytes;       // live through gather
    __half* xs   = (__half*)ws; ws += (size_t)n * 64 * 2;
    ushort* aggb = (ushort*)ws; ws += aggBytes;
    ushort* Mb   = (ushort*)ws; ws += 512 * 64 * 2;
    float* cb    = (float*)ws;  ws += 512 * 4;

    hist_build_kernel<<<nT + MBBLK, 512, 0, stream>>>(dsts, histg, E, B, nT,
                                                      Wz, bz, Wh, bh,
                                                      Lzw, Lzb, Lhw, Lhb, Mb, cb);
    colscan_kernel<<<B, 512, 0, stream>>>(histg, bdeg, nT);
    bucket_prefix_kernel<<<1, BMAX, 0, stream>>>(bdeg, bbase, B);
    scatter2_kernel<<<nT, 512, 0, stream>>>(srcs, dsts, histg, bbase, staging,
                                            E, B);
    prep_kernel<<<B, 512, 0, stream>>>(staging, bdeg, bbase, x, deg, xs, n, B);
    bucket_gather_kernel<<<2 * B, 512, 0, stream>>>(staging, bdeg, bbase, deg,
                                                    xs, aggb, n, B);
    node_mfma_kernel<<<1024, 512, 0, stream>>>(aggb, Mb, cb, Wo, bo, out, n);
}